// Round 1
// baseline (603.979 us; speedup 1.0000x reference)
//
#include <hip/hip_runtime.h>
#include <stdint.h>

// Problem constants (fixed by setup_inputs): B=4, C=256, H=W=64 -> HW=4096, vis=1024
#define B_   4
#define C_   256
#define HW_  4096
#define VIS_ 1024
#define BT   64    // output tile edge (q x k)
#define BK   32    // channel slice
#define LDP  68    // padded LDS row stride (floats): 64+4 keeps 16B alignment, breaks bank aliasing

// Map fp32 to a monotone-orderable u32 (total order matching float compare on finite values)
__device__ __forceinline__ unsigned mapf(float v) {
    unsigned u = __float_as_uint(v);
    return (u & 0x80000000u) ? ~u : (u | 0x80000000u);
}

__global__ void init_ws_kernel(unsigned long long* ws, int n) {
    int i = blockIdx.x * blockDim.x + threadIdx.x;
    if (i < n) ws[i] = 0ull;   // 0 is below any mapped finite score key
}

__global__ __launch_bounds__(256) void gemm_argmax_kernel(
    const float* __restrict__ Q, const float* __restrict__ K,
    float* __restrict__ out0, unsigned long long* __restrict__ ws)
{
    __shared__ float As[BK][LDP];                 // A tile: [c][q]
    __shared__ float Bs[BK][LDP];                 // B tile: [c][k]
    __shared__ unsigned long long red[BT][17];    // argmax reduce; 17 to avoid 32-bank aliasing

    const int t  = threadIdx.x;
    const int tx = t & 15;        // k-direction micro index
    const int ty = t >> 4;        // q-direction micro index
    const int k0 = blockIdx.x * BT;
    const int q0 = blockIdx.y * BT;
    const int b  = blockIdx.z;

    const float* Qb = Q + (size_t)b * C_ * HW_;
    const float* Kb = K + (size_t)b * C_ * HW_;

    float acc[4][4] = {{0.f,0.f,0.f,0.f},{0.f,0.f,0.f,0.f},{0.f,0.f,0.f,0.f},{0.f,0.f,0.f,0.f}};

    for (int c0 = 0; c0 < C_; c0 += BK) {
        // Stage 32x64 tiles of Q and K: 512 float4 each, 2 per thread, coalesced.
        #pragma unroll
        for (int i = 0; i < 2; ++i) {
            int idx = i * 256 + t;          // 0..511
            int row = idx >> 4;             // 0..31  (channel within slice)
            int col = (idx & 15) * 4;       // 0..60  (q/k within tile)
            const float4 a  = *(const float4*)(Qb + (size_t)(c0 + row) * HW_ + q0 + col);
            const float4 bv = *(const float4*)(Kb + (size_t)(c0 + row) * HW_ + k0 + col);
            *(float4*)(&As[row][col]) = a;
            *(float4*)(&Bs[row][col]) = bv;
        }
        __syncthreads();
        #pragma unroll
        for (int cc = 0; cc < BK; ++cc) {
            const float4 av = *(const float4*)(&As[cc][ty * 4]);   // broadcast across tx
            const float4 bv = *(const float4*)(&Bs[cc][tx * 4]);
            const float a_[4] = {av.x, av.y, av.z, av.w};
            const float b_[4] = {bv.x, bv.y, bv.z, bv.w};
            #pragma unroll
            for (int i = 0; i < 4; ++i)
                #pragma unroll
                for (int j = 0; j < 4; ++j)
                    acc[i][j] = fmaf(a_[i], b_[j], acc[i][j]);
        }
        __syncthreads();
    }

    // Epilogue 1: visible corner of S (blocks fully inside since 1024 % 64 == 0)
    if (q0 < VIS_ && k0 < VIS_) {
        #pragma unroll
        for (int i = 0; i < 4; ++i) {
            float4 v = make_float4(acc[i][0], acc[i][1], acc[i][2], acc[i][3]);
            size_t off = (size_t)b * VIS_ * VIS_ + (size_t)(q0 + ty * 4 + i) * VIS_ + (k0 + tx * 4);
            *(float4*)(out0 + off) = v;
        }
    }

    // Epilogue 2: per-row argmax over this block's 64 k-columns.
    // Key = (mapped value << 32) | (4095 - k): atomicMax picks larger value,
    // and on exact value ties the SMALLER k wins -> matches np.argmax first-occurrence.
    #pragma unroll
    for (int i = 0; i < 4; ++i) {
        float best = acc[i][0];
        int   bj   = 0;
        #pragma unroll
        for (int j = 1; j < 4; ++j)
            if (acc[i][j] > best) { best = acc[i][j]; bj = j; }   // strict > keeps smallest j on ties
        int kidx = k0 + tx * 4 + bj;
        unsigned long long key = ((unsigned long long)mapf(best) << 32)
                               | (unsigned)(HW_ - 1 - kidx);
        red[ty * 4 + i][tx] = key;
    }
    __syncthreads();
    if (t < BT) {
        unsigned long long best = red[t][0];
        #pragma unroll
        for (int j = 1; j < 16; ++j) {
            unsigned long long v = red[t][j];
            if (v > best) best = v;
        }
        atomicMax(&ws[(size_t)b * HW_ + q0 + t], best);
    }
}

__global__ void finalize_kernel(const unsigned long long* __restrict__ ws,
                                float* __restrict__ out1, int n) {
    int i = blockIdx.x * blockDim.x + threadIdx.x;
    if (i < n) {
        unsigned kinv = (unsigned)(ws[i] & 0xFFFFFFFFull);
        out1[i] = (float)(HW_ - 1 - (int)kinv);   // indices <= 4095: exact in fp32
    }
}

extern "C" void kernel_launch(void* const* d_in, const int* in_sizes, int n_in,
                              void* d_out, int out_size, void* d_ws, size_t ws_size,
                              hipStream_t stream) {
    const float* Q = (const float*)d_in[0];
    const float* K = (const float*)d_in[1];
    // d_in[2] (V) is unused by the reference.
    float* out0 = (float*)d_out;                              // S_vis: B x 1024 x 1024
    float* out1 = out0 + (size_t)B_ * VIS_ * VIS_;            // H_idx: B x 4096 (as float)
    unsigned long long* ws = (unsigned long long*)d_ws;       // B*HW packed argmax keys (128 KB)

    const int n = B_ * HW_;
    init_ws_kernel<<<(n + 255) / 256, 256, 0, stream>>>(ws, n);

    dim3 grid(HW_ / BT, HW_ / BT, B_);
    gemm_argmax_kernel<<<grid, 256, 0, stream>>>(Q, K, out0, ws);

    finalize_kernel<<<(n + 255) / 256, 256, 0, stream>>>(ws, out1, n);
}

// Round 2
// 233.779 us; speedup vs baseline: 2.5835x; 2.5835x over previous
//
#include <hip/hip_runtime.h>
#include <stdint.h>

// Problem constants: B=4, C=256, H=W=64 -> HW=4096, vis=1024
#define B_   4
#define C_   256
#define HW_  4096
#define VIS_ 1024
#define KE_  768      // expanded K: [hi,hi,lo] x [hi,lo,hi] f16 split

using half8   = __attribute__((ext_vector_type(8))) _Float16;
using floatx4 = __attribute__((ext_vector_type(4))) float;

__device__ __forceinline__ unsigned mapf(float v) {
    unsigned u = __float_as_uint(v);
    return (u & 0x80000000u) ? ~u : (u | 0x80000000u);
}

__global__ void init_ws_kernel(unsigned long long* ws, int n) {
    int i = blockIdx.x * blockDim.x + threadIdx.x;
    if (i < n) ws[i] = 0ull;
}

__global__ void finalize_kernel(const unsigned long long* __restrict__ ws,
                                float* __restrict__ out1, int n) {
    int i = blockIdx.x * blockDim.x + threadIdx.x;
    if (i < n) {
        unsigned kinv = (unsigned)(ws[i] & 0xFFFFFFFFull);
        out1[i] = (float)(HW_ - 1 - (int)kinv);
    }
}

// ---------------- f16-split MFMA path ----------------

// Transpose + split: src[b][c][hw] fp32 -> dst[b][hw][768] f16 with
// A segments [hi,hi,lo], B segments [hi,lo,hi].
__global__ __launch_bounds__(256) void split_transpose_kernel(
    const float* __restrict__ Q, const float* __restrict__ K,
    _Float16* __restrict__ Aexp, _Float16* __restrict__ Bexp)
{
    __shared__ float tile[64][65];   // [c][hw], pad 65 to break 8-col bank aliasing
    const int hw0 = blockIdx.x * 64;
    const int c0  = blockIdx.y * 64;
    const int z = blockIdx.z, b = z >> 1, which = z & 1;
    const float* src = (which ? K : Q) + (size_t)b * C_ * HW_;
    _Float16* dst = (which ? Bexp : Aexp) + (size_t)b * HW_ * KE_;
    const int t = threadIdx.x;

    #pragma unroll
    for (int i = 0; i < 4; ++i) {
        int c  = (t >> 4) + i * 16;
        int hw = (t & 15) * 4;
        float4 v = *(const float4*)(src + (size_t)(c0 + c) * HW_ + hw0 + hw);
        tile[c][hw] = v.x; tile[c][hw+1] = v.y; tile[c][hw+2] = v.z; tile[c][hw+3] = v.w;
    }
    __syncthreads();

    #pragma unroll
    for (int i = 0; i < 2; ++i) {
        int id  = t + i * 256;       // 0..511
        int row = id >> 3;           // hw within tile
        int c8  = (id & 7) * 8;      // c offset within 64
        half8 h8, l8;
        #pragma unroll
        for (int j = 0; j < 8; ++j) {
            float v = tile[c8 + j][row];
            _Float16 h = (_Float16)v;
            h8[j] = h;
            l8[j] = (_Float16)(v - (float)h);
        }
        _Float16* base = dst + (size_t)(hw0 + row) * KE_ + c0 + c8;
        *(half8*)(base + 0 * C_) = h8;
        *(half8*)(base + 1 * C_) = which ? l8 : h8;
        *(half8*)(base + 2 * C_) = which ? h8 : l8;
    }
}

__device__ __forceinline__ void gl2lds16(const _Float16* g, _Float16* l) {
    __builtin_amdgcn_global_load_lds(
        (const __attribute__((address_space(1))) void*)g,
        (__attribute__((address_space(3))) void*)l, 16, 0, 0);
}

__global__ __launch_bounds__(256, 2) void gemm_mfma_kernel(
    const _Float16* __restrict__ Aexp, const _Float16* __restrict__ Bexp,
    float* __restrict__ out0, unsigned long long* __restrict__ keys)
{
    __shared__ __align__(16) _Float16 Al[128 * 32];   // [row][k] k-contiguous, unpadded (global_load_lds)
    __shared__ __align__(16) _Float16 Bl[128 * 32];
    __shared__ unsigned long long red2[128][2];

    const int t    = threadIdx.x;
    const int lane = t & 63;
    const int wave = t >> 6;
    const int quad = lane >> 4;
    const int s    = lane & 15;
    const int wm   = (wave >> 1) * 64;   // wave's m-origin in 128-tile
    const int wn   = (wave & 1) * 64;    // wave's n-origin
    const int kt = blockIdx.x, qt = blockIdx.y, b = blockIdx.z;

    const _Float16* Ab = Aexp + (size_t)b * HW_ * KE_ + (size_t)(qt * 128) * KE_;
    const _Float16* Bb = Bexp + (size_t)b * HW_ * KE_ + (size_t)(kt * 128) * KE_;

    // staging: 512 16B-chunks per tile, 2 per thread; chunk c -> (row=c>>2, quad16=c&3)
    const int ca = t, cb = t + 256;
    const int ra = ca >> 2, oa = (ca & 3) * 8;
    const int rb = cb >> 2, ob = (cb & 3) * 8;

    floatx4 acc[4][4] = {};

    for (int it = 0; it < KE_ / 32; ++it) {
        const int k0 = it * 32;
        gl2lds16(Ab + (size_t)ra * KE_ + k0 + oa, Al + ca * 8);
        gl2lds16(Ab + (size_t)rb * KE_ + k0 + ob, Al + cb * 8);
        gl2lds16(Bb + (size_t)ra * KE_ + k0 + oa, Bl + ca * 8);
        gl2lds16(Bb + (size_t)rb * KE_ + k0 + ob, Bl + cb * 8);
        __syncthreads();

        half8 a[4], bf[4];
        #pragma unroll
        for (int mi = 0; mi < 4; ++mi)
            a[mi] = *(half8*)(Al + (wm + mi * 16 + s) * 32 + quad * 8);
        #pragma unroll
        for (int ni = 0; ni < 4; ++ni)
            bf[ni] = *(half8*)(Bl + (wn + ni * 16 + s) * 32 + quad * 8);
        #pragma unroll
        for (int mi = 0; mi < 4; ++mi)
            #pragma unroll
            for (int ni = 0; ni < 4; ++ni)
                acc[mi][ni] = __builtin_amdgcn_mfma_f32_16x16x32_f16(a[mi], bf[ni], acc[mi][ni], 0, 0, 0);
        __syncthreads();
    }

    // Epilogue 1: S_vis corner (C/D layout: col=s, row=quad*4+reg — m89-verified)
    if (qt < 8 && kt < 8) {
        #pragma unroll
        for (int mi = 0; mi < 4; ++mi)
            #pragma unroll
            for (int r = 0; r < 4; ++r) {
                int grow = qt * 128 + wm + mi * 16 + quad * 4 + r;
                float* orow = out0 + ((size_t)b * VIS_ + grow) * VIS_ + kt * 128;
                #pragma unroll
                for (int ni = 0; ni < 4; ++ni)
                    orow[wn + ni * 16 + s] = acc[mi][ni][r];
            }
    }

    // Epilogue 2: fused argmax. key = (mapf(val)<<32) | (4095-col): max key ==
    // largest value, smallest col on ties (np.argmax first-occurrence).
    #pragma unroll
    for (int mi = 0; mi < 4; ++mi) {
        #pragma unroll
        for (int r = 0; r < 4; ++r) {
            float best = acc[mi][0][r];
            int bcol = wn + s;
            #pragma unroll
            for (int ni = 1; ni < 4; ++ni) {
                float v = acc[mi][ni][r];
                if (v > best) { best = v; bcol = wn + ni * 16 + s; }
            }
            int gcol = kt * 128 + bcol;
            unsigned long long key = ((unsigned long long)mapf(best) << 32)
                                   | (unsigned)(HW_ - 1 - gcol);
            #pragma unroll
            for (int m = 1; m < 16; m <<= 1) {
                unsigned long long o = __shfl_xor(key, m, 64);
                if (o > key) key = o;
            }
            if (s == 0) red2[wm + mi * 16 + quad * 4 + r][wave & 1] = key;
        }
    }
    __syncthreads();
    if (t < 128) {
        unsigned long long k0v = red2[t][0], k1v = red2[t][1];
        unsigned long long kk = k0v > k1v ? k0v : k1v;
        atomicMax(&keys[(size_t)b * HW_ + qt * 128 + t], kk);
    }
}

// ---------------- fp32 fallback path (round-1, known-good) ----------------
#define BT   64
#define BK   32
#define LDP  68

__global__ __launch_bounds__(256) void gemm_argmax_kernel(
    const float* __restrict__ Q, const float* __restrict__ K,
    float* __restrict__ out0, unsigned long long* __restrict__ ws)
{
    __shared__ float As[BK][LDP];
    __shared__ float Bs[BK][LDP];
    __shared__ unsigned long long red[BT][17];

    const int t  = threadIdx.x;
    const int tx = t & 15;
    const int ty = t >> 4;
    const int k0 = blockIdx.x * BT;
    const int q0 = blockIdx.y * BT;
    const int b  = blockIdx.z;

    const float* Qb = Q + (size_t)b * C_ * HW_;
    const float* Kb = K + (size_t)b * C_ * HW_;

    float acc[4][4] = {{0.f},{0.f},{0.f},{0.f}};

    for (int c0 = 0; c0 < C_; c0 += BK) {
        #pragma unroll
        for (int i = 0; i < 2; ++i) {
            int idx = i * 256 + t;
            int row = idx >> 4;
            int col = (idx & 15) * 4;
            const float4 a  = *(const float4*)(Qb + (size_t)(c0 + row) * HW_ + q0 + col);
            const float4 bv = *(const float4*)(Kb + (size_t)(c0 + row) * HW_ + k0 + col);
            *(float4*)(&As[row][col]) = a;
            *(float4*)(&Bs[row][col]) = bv;
        }
        __syncthreads();
        #pragma unroll
        for (int cc = 0; cc < BK; ++cc) {
            const float4 av = *(const float4*)(&As[cc][ty * 4]);
            const float4 bv = *(const float4*)(&Bs[cc][tx * 4]);
            const float a_[4] = {av.x, av.y, av.z, av.w};
            const float b_[4] = {bv.x, bv.y, bv.z, bv.w};
            #pragma unroll
            for (int i = 0; i < 4; ++i)
                #pragma unroll
                for (int j = 0; j < 4; ++j)
                    acc[i][j] = fmaf(a_[i], b_[j], acc[i][j]);
        }
        __syncthreads();
    }

    if (q0 < VIS_ && k0 < VIS_) {
        #pragma unroll
        for (int i = 0; i < 4; ++i) {
            float4 v = make_float4(acc[i][0], acc[i][1], acc[i][2], acc[i][3]);
            size_t off = (size_t)b * VIS_ * VIS_ + (size_t)(q0 + ty * 4 + i) * VIS_ + (k0 + tx * 4);
            *(float4*)(out0 + off) = v;
        }
    }

    #pragma unroll
    for (int i = 0; i < 4; ++i) {
        float best = acc[i][0];
        int   bj   = 0;
        #pragma unroll
        for (int j = 1; j < 4; ++j)
            if (acc[i][j] > best) { best = acc[i][j]; bj = j; }
        int kidx = k0 + tx * 4 + bj;
        unsigned long long key = ((unsigned long long)mapf(best) << 32)
                               | (unsigned)(HW_ - 1 - kidx);
        red[ty * 4 + i][tx] = key;
    }
    __syncthreads();
    if (t < BT) {
        unsigned long long best = red[t][0];
        #pragma unroll
        for (int j = 1; j < 16; ++j) {
            unsigned long long v = red[t][j];
            if (v > best) best = v;
        }
        atomicMax(&ws[(size_t)b * HW_ + q0 + t], best);
    }
}

extern "C" void kernel_launch(void* const* d_in, const int* in_sizes, int n_in,
                              void* d_out, int out_size, void* d_ws, size_t ws_size,
                              hipStream_t stream) {
    const float* Q = (const float*)d_in[0];
    const float* K = (const float*)d_in[1];
    float* out0 = (float*)d_out;
    float* out1 = out0 + (size_t)B_ * VIS_ * VIS_;

    unsigned long long* keys = (unsigned long long*)d_ws;     // 128 KB
    const size_t keys_bytes = (size_t)B_ * HW_ * 8;
    const size_t exp_elems  = (size_t)B_ * HW_ * KE_;
    const size_t need = keys_bytes + 2 * exp_elems * sizeof(_Float16);

    const int n = B_ * HW_;
    init_ws_kernel<<<(n + 255) / 256, 256, 0, stream>>>(keys, n);

    if (ws_size >= need) {
        _Float16* Aexp = (_Float16*)((char*)d_ws + keys_bytes);
        _Float16* Bexp = Aexp + exp_elems;
        split_transpose_kernel<<<dim3(HW_ / 64, C_ / 64, 2 * B_), 256, 0, stream>>>(Q, K, Aexp, Bexp);
        gemm_mfma_kernel<<<dim3(HW_ / 128, HW_ / 128, B_), 256, 0, stream>>>(Aexp, Bexp, out0, keys);
    } else {
        gemm_argmax_kernel<<<dim3(HW_ / BT, HW_ / BT, B_), 256, 0, stream>>>(Q, K, out0, keys);
    }

    finalize_kernel<<<(n + 255) / 256, 256, 0, stream>>>(keys, out1, n);
}